// Round 15
// baseline (219.279 us; speedup 1.0000x reference)
//
#include <hip/hip_runtime.h>
#include <hip/hip_cooperative_groups.h>
#include <stdint.h>

// ContinuousConvolution, MI355X gfx950. Round 15: collapse the 6-dispatch
// build pipeline (memset/pack/count/scan/scatter/prep) into ONE cooperative
// kernel (128 blocks x 256 thr, 3 grid.sync()). knnmlp_kernel byte-identical
// to R14 (48 us, VALUBusy 55%). Output bit-identical: selection sorts exact
// (d2bits, idx) keys, absorbing scatter-order nondeterminism.

namespace cg = cooperative_groups;

typedef unsigned short u16;
typedef unsigned int   u32;
typedef unsigned long long u64;

#define NPTS  8192
#define KNB   16
#define SCAP  128

__device__ __forceinline__ float bf2f(u16 u) {
    union { u32 i; float f; } v; v.i = ((u32)u) << 16; return v.f;
}
__device__ __forceinline__ u16 f2bf(float f) {
    u32 x = __float_as_uint(f);
    return (u16)((x + 0x7FFFu + ((x >> 16) & 1u)) >> 16);  // RNE (lossless here)
}
__device__ __forceinline__ u32 fordkey(float f) {
    u32 u = __float_as_uint(f);
    return u ^ ((u32)((int)u >> 31) | 0x80000000u);
}
__device__ __forceinline__ u64 shflxor64(u64 v, int m) {
    int lo = __shfl_xor((int)(u32)v, m, 64);
    int hi = __shfl_xor((int)(u32)(v >> 32), m, 64);
    return ((u64)(u32)hi << 32) | (u32)lo;
}
// Reference-matching d2 (verified round 5): dot = Eigen FMA chain, rest strict.
__device__ __forceinline__ float sq_np32(float x, float y, float z) {
    return __fadd_rn(__fadd_rn(__fmul_rn(x, x), __fmul_rn(y, y)), __fmul_rn(z, z));
}
__device__ __forceinline__ float d2_ref(float qx, float qy, float qz, float qsq,
                                        float x, float y, float z, float sq) {
    float dot = fmaf(z, qz, fmaf(y, qy, __fmul_rn(x, qx)));
    return __fsub_rn(__fadd_rn(qsq, sq), __fmul_rn(2.0f, dot));
}
__device__ __forceinline__ int cellof(float v) {
    int c = (int)floorf(v * 8.0f);
    return c < 0 ? 0 : (c > 7 ? 7 : c);
}

// ---------------- Kernel 1: cooperative build ----------------
// 128 blocks x 256 threads. P0: zero counts + pack pfh + prep (block 127).
// P1: count. P2: scan (blocks 0,1 wave 0). P3: scatter.
__global__ __launch_bounds__(256) void build_kernel(
    const float* __restrict__ pf, const float* __restrict__ coords,
    const float* __restrict__ w1, const float* __restrict__ b1,
    const float* __restrict__ w2, const float* __restrict__ b2,
    const float* __restrict__ w3, const float* __restrict__ b3,
    u16* __restrict__ pfh, int* __restrict__ counts,
    int* __restrict__ cellStart, int* __restrict__ cellOffset,
    float4* __restrict__ spts, int* __restrict__ sidx,
    float* __restrict__ M, float* __restrict__ E) {

    cg::grid_group grid = cg::this_grid();
    const int blk = blockIdx.x;     // 0..127
    const int tid = threadIdx.x;    // 0..255

    // ---- P0: zero counts; pack pfh (float4); prep in block 127 ----
    if (blk < 4) counts[blk * 256 + tid] = 0;
    {
        const float4* pf4 = (const float4*)pf;      // 262144 float4
        ushort4* ph4 = (ushort4*)pfh;
#pragma unroll
        for (int i = 0; i < 8; ++i) {
            int g = (blk * 256 + tid) * 8 + i;      // 0..262143
            float4 v = pf4[g];
            ushort4 o;
            o.x = f2bf(v.x); o.y = f2bf(v.y); o.z = f2bf(v.z); o.w = f2bf(v.w);
            ph4[g] = o;
        }
    }
    if (blk == 127) {
        // prep: M = W3*W2*W1 (64x68), E = W3*(W2*b1+b2)+b3 (R14 bit-identical)
        __shared__ float W1s[32 * 67];
        __shared__ float W2s[64 * 32];
        __shared__ float W3s[64 * 64];
        __shared__ float T[64][68];
        __shared__ float tb2[64];
        for (int i = tid; i < 32 * 67; i += 256) W1s[i] = w1[i];
        for (int i = tid; i < 64 * 32; i += 256) W2s[i] = w2[i];
        for (int i = tid; i < 64 * 64; i += 256) W3s[i] = w3[i];
        __syncthreads();
#pragma unroll 1
        for (int e = tid; e < 64 * 67; e += 256) {
            int row = e / 67, c = e - row * 67;
            float acc = 0.0f;
#pragma unroll
            for (int i = 0; i < 32; ++i)
                acc = fmaf(W2s[row * 32 + i], W1s[i * 67 + c], acc);
            T[row][c] = acc;
        }
        if (tid < 64) {
            float accb = 0.0f;
#pragma unroll
            for (int i = 0; i < 32; ++i) accb = fmaf(W2s[tid * 32 + i], b1[i], accb);
            tb2[tid] = accb + b2[tid];
            T[tid][67] = 0.0f;
        }
        __syncthreads();
#pragma unroll 1
        for (int e = tid; e < 64 * 67; e += 256) {
            int row = e / 67, c = e - row * 67;
            float acc = 0.0f;
#pragma unroll
            for (int j = 0; j < 64; ++j)
                acc = fmaf(W3s[row * 64 + j], T[j][c], acc);
            M[row * 68 + c] = acc;
        }
        if (tid < 64) {
            M[tid * 68 + 67] = 0.0f;
            float e2 = 0.0f;
#pragma unroll
            for (int j = 0; j < 64; ++j) e2 = fmaf(W3s[tid * 64 + j], tb2[j], e2);
            E[tid] = e2 + b3[tid];
        }
    }
    grid.sync();

    // ---- P1: count (16384 pts / 128 blocks = 128/block) ----
    if (tid < 128) {
        int gid = blk * 128 + tid;
        float x = coords[gid * 3 + 0];
        float y = coords[gid * 3 + 1];
        float z = coords[gid * 3 + 2];
        int b = gid >> 13;
        int cell = (cellof(x) * 8 + cellof(y)) * 8 + cellof(z);
        atomicAdd(&counts[b * 512 + cell], 1);
    }
    grid.sync();

    // ---- P2: scan (blocks 0,1; wave 0; 8 chunks of 64 via shfl scan) ----
    if (blk < 2 && tid < 64) {
        const int lane = tid;
        int running = 0;
#pragma unroll 1
        for (int c = 0; c < 8; ++c) {
            int idx = blk * 512 + c * 64 + lane;
            int val = counts[idx];
            int incl = val;
#pragma unroll
            for (int d = 1; d < 64; d <<= 1) {
                int o = __shfl_up(incl, d, 64);
                if (lane >= d) incl += o;
            }
            int excl = running + incl - val;
            cellStart[blk * 513 + c * 64 + lane] = excl;
            cellOffset[blk * 512 + c * 64 + lane] = excl;
            running += __shfl(incl, 63, 64);
        }
        if (lane == 0) cellStart[blk * 513 + 512] = running;
    }
    grid.sync();

    // ---- P3: scatter ----
    if (tid < 128) {
        int gid = blk * 128 + tid;
        float x = coords[gid * 3 + 0];
        float y = coords[gid * 3 + 1];
        float z = coords[gid * 3 + 2];
        int b = gid >> 13, i = gid & (NPTS - 1);
        int cell = (cellof(x) * 8 + cellof(y)) * 8 + cellof(z);
        int pos = atomicAdd(&cellOffset[b * 512 + cell], 1);
        spts[b * NPTS + pos] = make_float4(x, y, z, sq_np32(x, y, z));
        sidx[b * NPTS + pos] = i;
    }
}

// ---------------- Kernel 2: fused knn + collapsed mlp (unchanged R14) --------
// 8192 blocks x 128 threads = 2 independent waves, 1 query per wave.
__global__ __launch_bounds__(128) void knnmlp_kernel(
    const float* __restrict__ coords, const float4* __restrict__ spts,
    const int* __restrict__ sidx, const int* __restrict__ cellStart,
    const u16* __restrict__ pfh, const float* __restrict__ M,
    const float* __restrict__ E, const float* __restrict__ aw,
    const float* __restrict__ ab, float* __restrict__ out) {

    __shared__ u64 surv[2][SCAP];
    __shared__ __attribute__((aligned(16))) float vb[2][2][68];

    const int lane = threadIdx.x & 63;
    const int wv   = threadIdx.x >> 6;
    // XCD chunk swizzle over sorted positions (grid 8192 = 8 x 1024)
    const int sblk = ((int)blockIdx.x & 7) * 1024 + ((int)blockIdx.x >> 3);
    const int pos  = sblk * 2 + wv;            // 0..16383 sorted position
    const int b    = pos >> 13;
    const int p    = pos & (NPTS - 1);
    const float*  cb = coords + (size_t)b * NPTS * 3;
    const float4* sp = spts + b * NPTS;
    const int*    si = sidx + b * NPTS;
    const int*    cs = cellStart + b * 513;
    u64* sv = surv[wv];

    const int q = si[p];
    float qx = cb[q * 3 + 0], qy = cb[q * 3 + 1], qz = cb[q * 3 + 2];
    float qsq = sq_np32(qx, qy, qz);
    int cqx = cellof(qx), cqy = cellof(qy), cqz = cellof(qz);

    // PASS A: lane-minima over 3^3 cell box -> conservative tau (R9-exact)
    int ax0 = max(cqx - 1, 0), ax1 = min(cqx + 1, 7);
    int ay0 = max(cqy - 1, 0), ay1 = min(cqy + 1, 7);
    int az0 = max(cqz - 1, 0), az1 = min(cqz + 1, 7);
    float dmin = 3.0e38f;
#pragma unroll 1
    for (int cx = ax0; cx <= ax1; ++cx)
#pragma unroll 1
        for (int cy = ay0; cy <= ay1; ++cy) {
            int base = (cx * 8 + cy) * 8;
            int s = cs[base + az0], e = cs[base + az1 + 1];
            for (int i0 = s; i0 < e; i0 += 64) {
                int i = i0 + lane;
                int ii = (i < e) ? i : (e - 1);
                float4 c = sp[ii];
                float d2 = d2_ref(qx, qy, qz, qsq, c.x, c.y, c.z, c.w);
                if (i < e) dmin = fminf(dmin, d2);
            }
        }
    {   // wave bitonic sort-64 ascending
        float v = dmin;
#pragma unroll
        for (int k = 2; k <= 64; k <<= 1) {
#pragma unroll
            for (int j2 = k >> 1; j2 >= 1; j2 >>= 1) {
                float o = __shfl_xor(v, j2, 64);
                bool lo = (lane & j2) == 0;
                bool up = (lane & k) == 0;
                float mn = fminf(v, o), mx = fmaxf(v, o);
                v = (lo == up) ? mn : mx;
            }
        }
        dmin = __shfl(v, 15, 64);              // 16th smallest lane-min
    }
    const float tau = dmin;                     // >= true 16th-NN d2

    // PASS B: wave-uniform filter scan over rr-box, d2 <= tau
    float rr = sqrtf(tau + 1e-5f) + 1e-6f;
    int bx0 = max((int)floorf((qx - rr) * 8.0f), 0);
    int bx1 = min((int)floorf((qx + rr) * 8.0f), 7);
    int by0 = max((int)floorf((qy - rr) * 8.0f), 0);
    int by1 = min((int)floorf((qy + rr) * 8.0f), 7);
    int bz0 = max((int)floorf((qz - rr) * 8.0f), 0);
    int bz1 = min((int)floorf((qz + rr) * 8.0f), 7);
    int cnt = 0;
#pragma unroll 1
    for (int cx = bx0; cx <= bx1; ++cx)
#pragma unroll 1
        for (int cy = by0; cy <= by1; ++cy) {
            int base = (cx * 8 + cy) * 8;
            int s = cs[base + bz0], e = cs[base + bz1 + 1];
            for (int i0 = s; i0 < e; i0 += 64) {
                int i = i0 + lane;
                bool valid = (i < e);
                int ii = valid ? i : (e - 1);
                float4 c = sp[ii];
                float d2 = d2_ref(qx, qy, qz, qsq, c.x, c.y, c.z, c.w);
                bool pass = valid && (d2 <= tau);
                u64 mask = __ballot(pass);
                if (pass) {
                    int pre = __builtin_amdgcn_mbcnt_hi((u32)(mask >> 32),
                              __builtin_amdgcn_mbcnt_lo((u32)mask, 0));
                    int pp = cnt + pre;
                    if (pp < SCAP)
                        sv[pp] = ((u64)fordkey(d2) << 32) | (u32)si[ii];
                }
                cnt += (int)__popcll(mask);
            }
        }
    __threadfence_block();

    // exact top-16 by (d2bits, idx)
    int myidx = 0;
    if (cnt <= 64) {
        u64 key = (lane < cnt) ? sv[lane] : ~0ull;
#pragma unroll
        for (int k = 2; k <= 64; k <<= 1) {
#pragma unroll
            for (int j2 = k >> 1; j2 >= 1; j2 >>= 1) {
                u64 o = shflxor64(key, j2);
                bool lo = (lane & j2) == 0;
                bool up = (lane & k) == 0;
                bool takemin = (lo == up);
                key = ((o < key) == takemin) ? o : key;
            }
        }
        myidx = (int)(u32)(key & 0xffffffffu);  // lanes 0..15 = top-16 asc
    } else {
        int cc = cnt > SCAP ? SCAP : cnt;
        u64 a0 = (lane < cc) ? sv[lane] : ~0ull;
        u64 a1 = (64 + lane < cc) ? sv[64 + lane] : ~0ull;
        if (a1 < a0) { u64 tmp = a0; a0 = a1; a1 = tmp; }
#pragma unroll 1
        for (int r2 = 0; r2 < 16; ++r2) {
            u64 mm = a0;
#pragma unroll
            for (int d = 1; d < 64; d <<= 1) {
                u64 o = shflxor64(mm, d);
                mm = (o < mm) ? o : mm;
            }
            if (a0 == mm) { a0 = a1; a1 = ~0ull; }
            if (lane == r2) myidx = (int)(u32)(mm & 0xffffffffu);
        }
    }

    __builtin_amdgcn_sched_barrier(0);          // keep mlp loads out of knn phase

    // ---------------- collapsed MLP ----------------
    float awr[16];
#pragma unroll
    for (int k = 0; k < 16; ++k) awr[k] = aw[k];
    float sa = 0.0f;
#pragma unroll
    for (int k = 0; k < 16; ++k) sa += awr[k];
    const float ev = E[lane], abv = ab[0];
    const u16* pfb = pfh + (size_t)b * NPTS * 64;

    float pool = -3.0e38f, G1 = 0.0f, Ga = 0.0f;
#pragma unroll
    for (int k = 0; k < 16; ++k) {
        int nk = __shfl(myidx, k, 64);
        float v = bf2f(pfb[nk * 64 + lane]);
        pool = fmaxf(pool, v);
        G1 += v;
        Ga = fmaf(awr[k], v, Ga);
    }
    float* v0 = vb[wv][0];
    float* v1 = vb[wv][1];
    v0[lane] = G1;
    v1[lane] = Ga;
    if (lane < 48) {
        int j1 = lane >> 4;
        int nk2 = __shfl(myidx, lane & 15, 64);
        int i0  = __shfl(myidx, 0, 64);
        float rel  = cb[nk2 * 3 + j1] - cb[i0 * 3 + j1];
        float wrel = awr[lane & 15] * rel;
#pragma unroll
        for (int d = 1; d < 16; d <<= 1) {
            rel  += __shfl_xor(rel, d, 64);
            wrel += __shfl_xor(wrel, d, 64);
        }
        if ((lane & 15) == 0) { v0[64 + j1] = rel; v1[64 + j1] = wrel; }
    }
    if (lane == 0) { v0[67] = 0.0f; v1[67] = 0.0f; }
    __threadfence_block();

    // one matvec on both vectors: lane = output channel, M row in registers
    float s1 = 16.0f * ev, sA = sa * ev;
    {
        const float4* mp = (const float4*)(M + lane * 68);   // 17 aligned float4
        const float4* p0 = (const float4*)v0;
        const float4* p1 = (const float4*)v1;
#pragma unroll
        for (int c4 = 0; c4 < 17; ++c4) {
            float4 mr = mp[c4];
            float4 x0 = p0[c4], x1 = p1[c4];
            s1 = fmaf(x0.x, mr.x, s1); s1 = fmaf(x0.y, mr.y, s1);
            s1 = fmaf(x0.z, mr.z, s1); s1 = fmaf(x0.w, mr.w, s1);
            sA = fmaf(x1.x, mr.x, sA); sA = fmaf(x1.y, mr.y, sA);
            sA = fmaf(x1.z, mr.z, sA); sA = fmaf(x1.w, mr.w, sA);
        }
    }
    float* op = out + ((size_t)b * NPTS + q) * 192;
    op[lane]       = s1;
    op[64 + lane]  = pool;
    op[128 + lane] = sA + abv;
}

extern "C" void kernel_launch(void* const* d_in, const int* in_sizes, int n_in,
                              void* d_out, int out_size, void* d_ws, size_t ws_size,
                              hipStream_t stream) {
    const float* pf     = (const float*)d_in[0];
    const float* coords = (const float*)d_in[1];
    const float* w1     = (const float*)d_in[2];
    const float* b1     = (const float*)d_in[3];
    const float* w2     = (const float*)d_in[4];
    const float* b2     = (const float*)d_in[5];
    const float* w3     = (const float*)d_in[6];
    const float* b3     = (const float*)d_in[7];
    const float* aw     = (const float*)d_in[8];
    const float* ab     = (const float*)d_in[9];

    char* ws = (char*)d_ws;
    u16*    pfh        = (u16*)ws;                              // 2 MB
    float4* spts       = (float4*)(ws + (2 << 20));             // 256 KB
    int*    sidx       = (int*)(ws + (2 << 20) + (256 << 10));  // 64 KB
    int*    cellStart  = (int*)(ws + (2 << 20) + (320 << 10));  // 2*513*4 B
    int*    counts     = (int*)(ws + (2 << 20) + (328 << 10));  // 2*512*4 B
    int*    cellOffset = (int*)(ws + (2 << 20) + (336 << 10));  // 2*512*4 B
    float*  Mw         = (float*)(ws + (2 << 20) + (344 << 10)); // 64*68*4 B
    float*  Ew         = (float*)(ws + (2 << 20) + (364 << 10)); // 256 B
    float*  outp       = (float*)d_out;

    void* argsB[] = {
        (void*)&pf, (void*)&coords, (void*)&w1, (void*)&b1, (void*)&w2,
        (void*)&b2, (void*)&w3, (void*)&b3, (void*)&pfh, (void*)&counts,
        (void*)&cellStart, (void*)&cellOffset, (void*)&spts, (void*)&sidx,
        (void*)&Mw, (void*)&Ew
    };
    hipLaunchCooperativeKernel((const void*)build_kernel, dim3(128), dim3(256),
                               argsB, 0, stream);
    knnmlp_kernel<<<8192, 128, 0, stream>>>(coords, spts, sidx, cellStart, pfh,
                                            Mw, Ew, aw, ab, outp);
}